// Round 1
// baseline (293.089 us; speedup 1.0000x reference)
//
#include <hip/hip_runtime.h>

#define B_DIM 4
#define T_DIM 96
#define N_DIM 512
#define H_DIM 128
#define NH    (N_DIM * H_DIM)

// d_ws layout (in bf16 shorts):
#define WS_WEXP  0        // [256][128] bf16 row-major
#define WS_WCON  32768    // [128][128] bf16 row-major
#define WS_L     49152    // [96][96]  bf16 row-major: L[t][k] = 0.1*0.9^(t-k), k<=t
#define WS_TOTAL 58368

typedef __attribute__((ext_vector_type(8))) short short8;
typedef __attribute__((ext_vector_type(4))) float f32x4;

__device__ __forceinline__ unsigned short f2b_rh(float f) {
    union { float f; unsigned u; } c; c.f = f;
    return (unsigned short)((c.u + 0x8000u) >> 16);   // round-half-up to bf16
}
// pack two fp32 -> bf16x2 (low = a, high = b): 2 adds + 1 v_perm_b32
__device__ __forceinline__ unsigned pack_bf16_2(float a, float b) {
    union { float f; unsigned u; } ca, cb; ca.f = a; cb.f = b;
    return __builtin_amdgcn_perm(cb.u + 0x8000u, ca.u + 0x8000u, 0x07060302u);
}
__device__ __forceinline__ float u2f(unsigned u) {
    union { unsigned u; float f; } c; c.u = u;
    return c.f;
}

// ---- Prep: fp32 weights -> bf16 in ws; build EMA coefficient matrix L ----
extern "C" __global__ void prep_kernel(const float* __restrict__ Wexp,
                                       const float* __restrict__ Wcon,
                                       unsigned short* __restrict__ ws) {
    int i = blockIdx.x * 256 + threadIdx.x;
    if (i < 32768) {
        ws[WS_WEXP + i] = f2b_rh(Wexp[i]);
    } else if (i < 49152) {
        int j = i - 32768;
        ws[WS_WCON + j] = f2b_rh(Wcon[j]);
    } else if (i < WS_TOTAL) {
        int j = i - 49152;
        int t = j / 96, k = j - t * 96;
        float v = 0.0f;
        if (k <= t) v = 0.1f * __expf((float)(t - k) * -0.1053605157f); // 0.1*0.9^(t-k)
        ws[WS_L + j] = f2b_rh(v);
    }
}

// One 512-thread (8-wave) workgroup per (b, n).
// Wave w owns: GEMM1 primary o-tile w (o=16w..16w+15, kept IN REGISTERS, packed bf16),
//              GEMM1 gating o-tile 8+w  -> gateT rows h=16w..16w+15 (self-owned: no barrier),
//              EMA h-tile w, gating h-tile w, GEMM2 o-tile w.
// Biases deferred out of GEMM1: primary bias added at gating time; gating bias folded
// through the (linear) EMA as b*(1-0.9^{t+1}).
// Single __syncthreads() per block (pg is cross-wave for GEMM2 B-frags).
// MFMA 16x16x32 bf16 layouts: A[m=l16][k=q*8+j], B[k=q*8+j][n=l16], D[row=q*4+r][col=l16]
extern "C" __global__ __launch_bounds__(512, 6)
void mamba_fused(const float* __restrict__ x,
                 const unsigned short* __restrict__ ws,
                 const float* __restrict__ b_exp,
                 const float* __restrict__ b_con,
                 float* __restrict__ out)
{
    __shared__ __align__(16) unsigned short gateT[H_DIM * 104]; // [h][t'], stride 104 (13x16B rows)
    __shared__ __align__(16) unsigned short pg[T_DIM * 136];    // [t][h],  stride 136

    const int tid  = threadIdx.x;
    const int wave = tid >> 6;        // 0..7
    const int lane = tid & 63;
    const int q    = lane >> 4;
    const int l16  = lane & 15;

    const int blk = blockIdx.x;
    const int n   = blk & (N_DIM - 1);
    const int b   = blk >> 9;

    const float* xg = x + ((size_t)b * T_DIM * N_DIM + (size_t)n) * H_DIM;

    // ---- W_exp A-fragments: primary rows 16w.., gating rows 128+16w.. (bf16, no conversion) ----
    short8 wp[4], wg[4];
    {
        const unsigned short* wrp = ws + WS_WEXP + (size_t)(wave * 16 + l16) * H_DIM + q * 8;
        const unsigned short* wrg = wrp + 128 * H_DIM;
        for (int k0 = 0; k0 < 4; ++k0) {
            wp[k0] = *(const short8*)(wrp + k0 * 32);
            wg[k0] = *(const short8*)(wrg + k0 * 32);
        }
    }

    unsigned pacc[6][2];   // primary GEMM1 result, packed bf16x2, NO bias. [mt][2]

    // ---- GEMM1: x B-frags straight from global; primary -> regs, gating -> own gateT rows ----
    for (int mt = 0; mt < 6; ++mt) {
        const float* xrow = xg + (size_t)(mt * 16 + l16) * NH + q * 8;
        short8 bfr[4];
        for (int k0 = 0; k0 < 4; ++k0) {
            float4 v0 = *(const float4*)(xrow + k0 * 32);
            float4 v1 = *(const float4*)(xrow + k0 * 32 + 4);
            union { unsigned u[4]; short8 s; } p;
            p.u[0] = pack_bf16_2(v0.x, v0.y);
            p.u[1] = pack_bf16_2(v0.z, v0.w);
            p.u[2] = pack_bf16_2(v1.x, v1.y);
            p.u[3] = pack_bf16_2(v1.z, v1.w);
            bfr[k0] = p.s;
        }
        f32x4 ap = {0.f, 0.f, 0.f, 0.f};
        f32x4 ag = {0.f, 0.f, 0.f, 0.f};
        for (int k0 = 0; k0 < 4; ++k0) {
            ap = __builtin_amdgcn_mfma_f32_16x16x32_bf16(wp[k0], bfr[k0], ap, 0, 0, 0);
            ag = __builtin_amdgcn_mfma_f32_16x16x32_bf16(wg[k0], bfr[k0], ag, 0, 0, 0);
        }
        pacc[mt][0] = pack_bf16_2(ap[0], ap[1]);
        pacc[mt][1] = pack_bf16_2(ap[2], ap[3]);
        // gating D-frag (h=16w+q*4+r, t=mt*16+l16) -> gateT[h][t], rows owned by this wave
        unsigned short* gr = &gateT[(wave * 16 + q * 4) * 104 + mt * 16 + l16];
        gr[0]       = f2b_rh(ag[0]);
        gr[104]     = f2b_rh(ag[1]);
        gr[2 * 104] = f2b_rh(ag[2]);
        gr[3 * 104] = f2b_rh(ag[3]);
    }

    // Wave reads back only the gateT rows IT wrote: same-wave LDS ops complete in order,
    // so a waitcnt (no workgroup barrier) suffices.
    asm volatile("s_waitcnt lgkmcnt(0)" ::: "memory");
    __builtin_amdgcn_sched_barrier(0);

    // ---- EMA via MFMA: S^T[h][t] = G^T (A, m=h) x L^T (B, n=t), K=96 ----
    f32x4 eacc[6];
    for (int tt = 0; tt < 6; ++tt) eacc[tt] = (f32x4){0.f, 0.f, 0.f, 0.f};
    {
        const unsigned short* wsL = ws + WS_L;
        for (int kf = 0; kf < 3; ++kf) {
            short8 af = *(const short8*)&gateT[(wave * 16 + l16) * 104 + kf * 32 + q * 8];
            for (int tt = 0; tt < 6; ++tt) {
                short8 bf = *(const short8*)(wsL + (size_t)(tt * 16 + l16) * 96 + kf * 32 + q * 8);
                eacc[tt] = __builtin_amdgcn_mfma_f32_16x16x32_bf16(af, bf, eacc[tt], 0, 0, 0);
            }
        }
    }

    // ---- W_con frags + all biases (L2-hot loads, overlap with gating math) ----
    short8 wc[4];
    float4 bias2, bp, bg;
    {
        const unsigned short* wrc = ws + WS_WCON + (size_t)(wave * 16 + l16) * H_DIM + q * 8;
        for (int k0 = 0; k0 < 4; ++k0)
            wc[k0] = *(const short8*)(wrc + k0 * 32);
        bias2 = *(const float4*)(b_con + wave * 16 + q * 4);
        bp    = *(const float4*)(b_exp + wave * 16 + q * 4);
        bg    = *(const float4*)(b_exp + 128 + wave * 16 + q * 4);
    }

    // ---- gating: sigmoid(EMA + bg*(1-0.9^{t+1})) * (prim_reg + bp) -> pg[t][h] ----
    // pg is a separate buffer (no aliasing with gateT) -> no barrier needed before writes.
    for (int tt = 0; tt < 6; ++tt) {
        const int t = tt * 16 + l16;
        const float c = 1.0f - __expf((float)(t + 1) * -0.1053605157f); // 1-0.9^{t+1}
        f32x4 s = eacc[tt];
        float sg0 = __fdividef(1.f, 1.f + __expf(-(s[0] + bg.x * c)));
        float sg1 = __fdividef(1.f, 1.f + __expf(-(s[1] + bg.y * c)));
        float sg2 = __fdividef(1.f, 1.f + __expf(-(s[2] + bg.z * c)));
        float sg3 = __fdividef(1.f, 1.f + __expf(-(s[3] + bg.w * c)));
        unsigned u0 = pacc[tt][0], u1 = pacc[tt][1];
        float p0 = (u2f(u0 << 16)          + bp.x) * sg0;
        float p1 = (u2f(u0 & 0xffff0000u)  + bp.y) * sg1;
        float p2 = (u2f(u1 << 16)          + bp.z) * sg2;
        float p3 = (u2f(u1 & 0xffff0000u)  + bp.w) * sg3;
        union { unsigned u[2]; ushort4 s; } pk;
        pk.u[0] = pack_bf16_2(p0, p1);
        pk.u[1] = pack_bf16_2(p2, p3);
        *(ushort4*)&pg[t * 136 + wave * 16 + q * 4] = pk.s;
    }
    __syncthreads();   // the single cross-wave handoff: pg B-frags span all h

    // ---- GEMM2: out[o][t] = Wc @ pg^T + b ----
    float* og = out + ((size_t)b * T_DIM * N_DIM + (size_t)n) * H_DIM;
    for (int mt = 0; mt < 6; ++mt) {
        short8 bfr[4];
        const unsigned short* prow = &pg[(mt * 16 + l16) * 136];
        for (int k0 = 0; k0 < 4; ++k0)
            bfr[k0] = *(const short8*)(prow + k0 * 32 + q * 8);
        f32x4 acc = {0.f, 0.f, 0.f, 0.f};
        for (int k0 = 0; k0 < 4; ++k0)
            acc = __builtin_amdgcn_mfma_f32_16x16x32_bf16(wc[k0], bfr[k0], acc, 0, 0, 0);
        const int t = mt * 16 + l16;
        float4 v;
        v.x = acc[0] + bias2.x;
        v.y = acc[1] + bias2.y;
        v.z = acc[2] + bias2.z;
        v.w = acc[3] + bias2.w;
        *(float4*)(og + (size_t)t * NH + wave * 16 + q * 4) = v;
    }
}

extern "C" void kernel_launch(void* const* d_in, const int* in_sizes, int n_in,
                              void* d_out, int out_size, void* d_ws, size_t ws_size,
                              hipStream_t stream) {
    const float* x     = (const float*)d_in[0];
    const float* W_exp = (const float*)d_in[1];
    const float* b_exp = (const float*)d_in[2];
    const float* W_con = (const float*)d_in[3];
    const float* b_con = (const float*)d_in[4];
    float* out = (float*)d_out;
    unsigned short* ws = (unsigned short*)d_ws;

    hipLaunchKernelGGL(prep_kernel, dim3(WS_TOTAL / 256), dim3(256), 0, stream,
                       W_exp, W_con, ws);
    hipLaunchKernelGGL(mamba_fused, dim3(B_DIM * N_DIM), dim3(512), 0, stream,
                       x, ws, b_exp, b_con, out);
}

// Round 2
// 224.701 us; speedup vs baseline: 1.3044x; 1.3044x over previous
//
#include <hip/hip_runtime.h>

#define B_DIM 4
#define T_DIM 96
#define N_DIM 512
#define H_DIM 128
#define NH    (N_DIM * H_DIM)

// d_ws layout (in bf16 shorts):
#define WS_WEXP  0        // [256][128] bf16 row-major
#define WS_WCON  32768    // [128][128] bf16 row-major
#define WS_L     49152    // [96][96]  bf16 row-major: L[t][k] = 0.1*0.9^(t-k), k<=t
#define WS_TOTAL 58368

typedef __attribute__((ext_vector_type(8))) short short8;
typedef __attribute__((ext_vector_type(4))) float f32x4;

__device__ __forceinline__ unsigned short f2b_rh(float f) {
    union { float f; unsigned u; } c; c.f = f;
    return (unsigned short)((c.u + 0x8000u) >> 16);   // round-half-up to bf16
}
// pack two fp32 -> bf16x2 (low = a, high = b): 2 adds + 1 v_perm_b32
__device__ __forceinline__ unsigned pack_bf16_2(float a, float b) {
    union { float f; unsigned u; } ca, cb; ca.f = a; cb.f = b;
    return __builtin_amdgcn_perm(cb.u + 0x8000u, ca.u + 0x8000u, 0x07060302u);
}
__device__ __forceinline__ float u2f(unsigned u) {
    union { unsigned u; float f; } c; c.u = u;
    return c.f;
}

// ---- Prep: fp32 weights -> bf16 in ws; build EMA coefficient matrix L ----
extern "C" __global__ void prep_kernel(const float* __restrict__ Wexp,
                                       const float* __restrict__ Wcon,
                                       unsigned short* __restrict__ ws) {
    int i = blockIdx.x * 256 + threadIdx.x;
    if (i < 32768) {
        ws[WS_WEXP + i] = f2b_rh(Wexp[i]);
    } else if (i < 49152) {
        int j = i - 32768;
        ws[WS_WCON + j] = f2b_rh(Wcon[j]);
    } else if (i < WS_TOTAL) {
        int j = i - 49152;
        int t = j / 96, k = j - t * 96;
        float v = 0.0f;
        if (k <= t) v = 0.1f * __expf((float)(t - k) * -0.1053605157f); // 0.1*0.9^(t-k)
        ws[WS_L + j] = f2b_rh(v);
    }
}

// One 256-thread (4-wave) workgroup per (b, n).
// Wave w owns: primary o-tiles {2w,2w+1} (kept IN REGISTERS, packed bf16),
//              gating o-tiles {128+32w..} -> gateT rows h=32w..32w+31 (self-owned),
//              EMA h-tiles {2w,2w+1}, gating h-tiles {2w,2w+1}, GEMM2 o-tiles {2w,2w+1}.
// x-tile is staged ONCE cooperatively into LDS as bf16 (was: each wave re-read it from
// global and re-packed it -> 4x VMEM + 4x pack VALU).
// Biases deferred out of GEMM1; gating bias folded through linear EMA as b*(1-0.9^{t+1}).
// EMA MFMA tiles with kf*32 > tt*16+15 are all-zero (L lower-triangular) -> skipped.
// MFMA 16x16x32 bf16 layouts: A[m=l16][k=q*8+j], B[k=q*8+j][n=l16], D[row=q*4+r][col=l16]
extern "C" __global__ __launch_bounds__(256, 3)
void mamba_fused(const float* __restrict__ x,
                 const unsigned short* __restrict__ ws,
                 const float* __restrict__ b_exp,
                 const float* __restrict__ b_con,
                 float* __restrict__ out)
{
    __shared__ __align__(16) unsigned short gateT[H_DIM * 104]; // [h][t'], stride 104
    __shared__ __align__(16) unsigned short xpg[T_DIM * 136];   // x-tile bf16 [t][h]; later pg [t][h]

    const int tid  = threadIdx.x;
    const int wave = tid >> 6;        // 0..3
    const int lane = tid & 63;
    const int q    = lane >> 4;
    const int l16  = lane & 15;

    const int blk = blockIdx.x;
    const int n   = blk & (N_DIM - 1);
    const int b   = blk >> 9;

    const float* xg = x + ((size_t)b * T_DIM * N_DIM + (size_t)n) * H_DIM;

    // ---- Stage x-tile -> bf16 LDS, cooperatively (each row segment loaded ONCE) ----
    {
        const int r2    = lane >> 5;   // 0..1
        const int c     = lane & 31;   // 0..31 -> 4 floats each = full 128-col row
        const int rbase = wave * 2 + r2;
        #pragma unroll
        for (int i = 0; i < 12; ++i) {
            const int r = i * 8 + rbase;
            float4 v = *(const float4*)(xg + (size_t)r * NH + c * 4);
            union { unsigned u[2]; ushort4 s; } pk;
            pk.u[0] = pack_bf16_2(v.x, v.y);
            pk.u[1] = pack_bf16_2(v.z, v.w);
            *(ushort4*)&xpg[r * 136 + c * 4] = pk.s;
        }
    }

    // ---- W_exp A-fragments (bf16, L2-hot): primary rows {2w,2w+1}*16.., gating +128 ----
    short8 wp[2][4], wg[2][4];
    #pragma unroll
    for (int ot = 0; ot < 2; ++ot) {
        const unsigned short* wrp = ws + WS_WEXP + (size_t)((wave * 2 + ot) * 16 + l16) * H_DIM + q * 8;
        #pragma unroll
        for (int k0 = 0; k0 < 4; ++k0) {
            wp[ot][k0] = *(const short8*)(wrp + k0 * 32);
            wg[ot][k0] = *(const short8*)(wrp + 128 * H_DIM + k0 * 32);
        }
    }
    __syncthreads();   // x-tile staged

    unsigned pacc[2][6][2];   // primary GEMM1 result, packed bf16x2, NO bias. [ot][mt][2]

    // ---- GEMM1: B-frags from LDS; primary -> regs, gating -> own gateT rows ----
    #pragma unroll
    for (int mt = 0; mt < 6; ++mt) {
        short8 bfr[4];
        #pragma unroll
        for (int k0 = 0; k0 < 4; ++k0)
            bfr[k0] = *(const short8*)&xpg[(mt * 16 + l16) * 136 + k0 * 32 + q * 8];
        f32x4 ap0 = {0.f,0.f,0.f,0.f}, ap1 = {0.f,0.f,0.f,0.f};
        f32x4 ag0 = {0.f,0.f,0.f,0.f}, ag1 = {0.f,0.f,0.f,0.f};
        #pragma unroll
        for (int k0 = 0; k0 < 4; ++k0) {
            ap0 = __builtin_amdgcn_mfma_f32_16x16x32_bf16(wp[0][k0], bfr[k0], ap0, 0, 0, 0);
            ap1 = __builtin_amdgcn_mfma_f32_16x16x32_bf16(wp[1][k0], bfr[k0], ap1, 0, 0, 0);
            ag0 = __builtin_amdgcn_mfma_f32_16x16x32_bf16(wg[0][k0], bfr[k0], ag0, 0, 0, 0);
            ag1 = __builtin_amdgcn_mfma_f32_16x16x32_bf16(wg[1][k0], bfr[k0], ag1, 0, 0, 0);
        }
        pacc[0][mt][0] = pack_bf16_2(ap0[0], ap0[1]);
        pacc[0][mt][1] = pack_bf16_2(ap0[2], ap0[3]);
        pacc[1][mt][0] = pack_bf16_2(ap1[0], ap1[1]);
        pacc[1][mt][1] = pack_bf16_2(ap1[2], ap1[3]);
        // gating D-frags -> gateT[h][t], rows h=32w..32w+31 owned by this wave
        unsigned short* gr0 = &gateT[((wave * 2 + 0) * 16 + q * 4) * 104 + mt * 16 + l16];
        gr0[0]       = f2b_rh(ag0[0]);
        gr0[104]     = f2b_rh(ag0[1]);
        gr0[2 * 104] = f2b_rh(ag0[2]);
        gr0[3 * 104] = f2b_rh(ag0[3]);
        unsigned short* gr1 = &gateT[((wave * 2 + 1) * 16 + q * 4) * 104 + mt * 16 + l16];
        gr1[0]       = f2b_rh(ag1[0]);
        gr1[104]     = f2b_rh(ag1[1]);
        gr1[2 * 104] = f2b_rh(ag1[2]);
        gr1[3 * 104] = f2b_rh(ag1[3]);
    }

    // Wave reads back only the gateT rows IT wrote: same-wave LDS ops complete in
    // order after a drain -> waitcnt (no workgroup barrier).
    asm volatile("s_waitcnt lgkmcnt(0)" ::: "memory");
    __builtin_amdgcn_sched_barrier(0);

    // ---- EMA via MFMA: S^T[h][t] = G^T (A, m=h) x L^T (B, n=t), K=96, triangular-pruned ----
    f32x4 eacc[2][6];
    #pragma unroll
    for (int ht = 0; ht < 2; ++ht)
        #pragma unroll
        for (int tt = 0; tt < 6; ++tt)
            eacc[ht][tt] = (f32x4){0.f, 0.f, 0.f, 0.f};
    {
        const unsigned short* wsL = ws + WS_L;
        #pragma unroll
        for (int kf = 0; kf < 3; ++kf) {
            short8 af0 = *(const short8*)&gateT[((wave * 2 + 0) * 16 + l16) * 104 + kf * 32 + q * 8];
            short8 af1 = *(const short8*)&gateT[((wave * 2 + 1) * 16 + l16) * 104 + kf * 32 + q * 8];
            #pragma unroll
            for (int tt = 0; tt < 6; ++tt) {
                if (tt < 2 * kf) continue;   // L[t][k]==0 for whole tile (k > t)
                short8 bf = *(const short8*)(wsL + (size_t)(tt * 16 + l16) * 96 + kf * 32 + q * 8);
                eacc[0][tt] = __builtin_amdgcn_mfma_f32_16x16x32_bf16(af0, bf, eacc[0][tt], 0, 0, 0);
                eacc[1][tt] = __builtin_amdgcn_mfma_f32_16x16x32_bf16(af1, bf, eacc[1][tt], 0, 0, 0);
            }
        }
    }

    // ---- W_con frags + all biases (L2-hot; overlap the barrier wait) ----
    short8 wc[2][4];
    float4 bias2[2], bp[2], bgv[2];
    #pragma unroll
    for (int ot = 0; ot < 2; ++ot) {
        const int o = (wave * 2 + ot) * 16;
        const unsigned short* wrc = ws + WS_WCON + (size_t)(o + l16) * H_DIM + q * 8;
        #pragma unroll
        for (int k0 = 0; k0 < 4; ++k0)
            wc[ot][k0] = *(const short8*)(wrc + k0 * 32);
        bias2[ot] = *(const float4*)(b_con + o + q * 4);
        bp[ot]    = *(const float4*)(b_exp + o + q * 4);
        bgv[ot]   = *(const float4*)(b_exp + 128 + o + q * 4);
    }
    __syncthreads();   // all waves done reading xpg (GEMM1) -> safe to overwrite with pg

    // ---- gating: sigmoid(EMA + bg*(1-0.9^{t+1})) * (prim_reg + bp) -> pg[t][h] ----
    #pragma unroll
    for (int ot = 0; ot < 2; ++ot) {
        const int hb = (wave * 2 + ot) * 16 + q * 4;
        #pragma unroll
        for (int tt = 0; tt < 6; ++tt) {
            const int t = tt * 16 + l16;
            const float c = 1.0f - __expf((float)(t + 1) * -0.1053605157f); // 1-0.9^{t+1}
            f32x4 s = eacc[ot][tt];
            float sg0 = __fdividef(1.f, 1.f + __expf(-(s[0] + bgv[ot].x * c)));
            float sg1 = __fdividef(1.f, 1.f + __expf(-(s[1] + bgv[ot].y * c)));
            float sg2 = __fdividef(1.f, 1.f + __expf(-(s[2] + bgv[ot].z * c)));
            float sg3 = __fdividef(1.f, 1.f + __expf(-(s[3] + bgv[ot].w * c)));
            unsigned u0 = pacc[ot][tt][0], u1 = pacc[ot][tt][1];
            float p0 = (u2f(u0 << 16)         + bp[ot].x) * sg0;
            float p1 = (u2f(u0 & 0xffff0000u) + bp[ot].y) * sg1;
            float p2 = (u2f(u1 << 16)         + bp[ot].z) * sg2;
            float p3 = (u2f(u1 & 0xffff0000u) + bp[ot].w) * sg3;
            union { unsigned u[2]; ushort4 s; } pk;
            pk.u[0] = pack_bf16_2(p0, p1);
            pk.u[1] = pack_bf16_2(p2, p3);
            *(ushort4*)&xpg[t * 136 + hb] = pk.s;
        }
    }
    __syncthreads();   // cross-wave handoff: pg B-frags span all h

    // ---- GEMM2: out[o][t] = Wc @ pg^T + b ----
    float* og = out + ((size_t)b * T_DIM * N_DIM + (size_t)n) * H_DIM;
    #pragma unroll
    for (int mt = 0; mt < 6; ++mt) {
        short8 bfr[4];
        const unsigned short* prow = &xpg[(mt * 16 + l16) * 136];
        #pragma unroll
        for (int k0 = 0; k0 < 4; ++k0)
            bfr[k0] = *(const short8*)(prow + k0 * 32 + q * 8);
        const int t = mt * 16 + l16;
        #pragma unroll
        for (int ot = 0; ot < 2; ++ot) {
            f32x4 acc = {0.f, 0.f, 0.f, 0.f};
            #pragma unroll
            for (int k0 = 0; k0 < 4; ++k0)
                acc = __builtin_amdgcn_mfma_f32_16x16x32_bf16(wc[ot][k0], bfr[k0], acc, 0, 0, 0);
            const int o = (wave * 2 + ot) * 16 + q * 4;
            float4 v;
            v.x = acc[0] + bias2[ot].x;
            v.y = acc[1] + bias2[ot].y;
            v.z = acc[2] + bias2[ot].z;
            v.w = acc[3] + bias2[ot].w;
            *(float4*)(og + (size_t)t * NH + o) = v;
        }
    }
}

extern "C" void kernel_launch(void* const* d_in, const int* in_sizes, int n_in,
                              void* d_out, int out_size, void* d_ws, size_t ws_size,
                              hipStream_t stream) {
    const float* x     = (const float*)d_in[0];
    const float* W_exp = (const float*)d_in[1];
    const float* b_exp = (const float*)d_in[2];
    const float* W_con = (const float*)d_in[3];
    const float* b_con = (const float*)d_in[4];
    float* out = (float*)d_out;
    unsigned short* ws = (unsigned short*)d_ws;

    hipLaunchKernelGGL(prep_kernel, dim3(WS_TOTAL / 256), dim3(256), 0, stream,
                       W_exp, W_con, ws);
    hipLaunchKernelGGL(mamba_fused, dim3(B_DIM * N_DIM), dim3(256), 0, stream,
                       x, ws, b_exp, b_con, out);
}